// Round 5
// baseline (439.560 us; speedup 1.0000x reference)
//
#include <hip/hip_runtime.h>
#include <hip/hip_cooperative_groups.h>
#include <hip/hip_bf16.h>
#include <math.h>

namespace cg = cooperative_groups;

#define N_NODES 8192
#define DIM 256
#define WPR 256   // bitmap words per row = 8192/32
#define MAXD 128  // max deduped neighbors per row (deduped degree ~ Poisson(33); P(>=128) ~ 0)
#define EPS 1e-5f
#define NBLK 512
#define NTHR 256
#define NTHREADS (NBLK * NTHR)  // 131072

typedef __attribute__((ext_vector_type(8))) short bf16x8;
typedef __attribute__((ext_vector_type(4))) float f32x4;

__device__ inline bf16x8 pack8(float4 lo, float4 hi) {
    union { __hip_bfloat16 h[8]; bf16x8 v; } u;
    u.h[0] = __float2bfloat16(lo.x); u.h[1] = __float2bfloat16(lo.y);
    u.h[2] = __float2bfloat16(lo.z); u.h[3] = __float2bfloat16(lo.w);
    u.h[4] = __float2bfloat16(hi.x); u.h[5] = __float2bfloat16(hi.y);
    u.h[6] = __float2bfloat16(hi.z); u.h[7] = __float2bfloat16(hi.w);
    return u.v;
}

__device__ inline float bfhi(unsigned u) { return __uint_as_float(u & 0xffff0000u); }
__device__ inline float bflo(unsigned u) { return __uint_as_float(u << 16); }

// One cooperative dispatch: zero -> scatter(dedup CSR) -> gemm(MFMA, fused dinv) -> aggregate
__global__ __launch_bounds__(NTHR, 2) void gcn_fused(
    const float* __restrict__ x,
    const int* __restrict__ erows, const int* __restrict__ ecols,
    const float* __restrict__ W, float* __restrict__ out,
    unsigned* __restrict__ bitmap, int* __restrict__ degree,
    int* __restrict__ cols, __hip_bfloat16* __restrict__ g, int E) {

    cg::grid_group grid = cg::this_grid();
    const int tid = blockIdx.x * NTHR + threadIdx.x;  // 0..131071

    // ---- phase 0: zero bitmap + degree (contiguous, 8 MB + 32 KB) ----
    {
        uint4 z = make_uint4(0, 0, 0, 0);
        uint4* zb = (uint4*)bitmap;
        const int nv = (N_NODES * WPR + N_NODES) / 4;  // 526336 uint4
        for (int i = tid; i < nv; i += NTHREADS) zb[i] = z;
    }
    __threadfence();
    grid.sync();

    // ---- phase 1: scatter edges + diagonal; dedup via atomicOr old-value; build CSR ----
    {
        const int total = E + N_NODES;
        for (int t = tid; t < total; t += NTHREADS) {
            int r, c;
            if (t < E) { r = erows[t]; c = ecols[t]; }
            else       { r = t - E;   c = r; }
            unsigned bit = 1u << (c & 31);
            unsigned old = atomicOr(&bitmap[(size_t)r * WPR + (c >> 5)], bit);
            if (!(old & bit)) {
                int p = atomicAdd(&degree[r], 1);
                cols[(size_t)r * MAXD + p] = c;
            }
        }
    }
    __threadfence();
    grid.sync();

    // ---- phase 2: g = bf16( rsqrt(deg) .* (x @ W^T) ); 512 tiles of 64m x 64n ----
    {
        int wave = threadIdx.x >> 6;
        int lane = threadIdx.x & 63;
        int bm = (blockIdx.x >> 2) * 64 + wave * 16;
        int bn = (blockIdx.x & 3) * 64;
        int quad = lane >> 4;
        int l16 = lane & 15;
        f32x4 acc[4] = {};
        const float* arow = x + (size_t)(bm + l16) * DIM + quad * 8;
#pragma unroll
        for (int k0 = 0; k0 < DIM; k0 += 32) {
            float4 a0 = *(const float4*)(arow + k0);
            float4 a1 = *(const float4*)(arow + k0 + 4);
            bf16x8 a = pack8(a0, a1);
#pragma unroll
            for (int s = 0; s < 4; s++) {
                const float* brow = W + (size_t)(bn + s * 16 + l16) * DIM + quad * 8 + k0;
                bf16x8 b = pack8(*(const float4*)(brow), *(const float4*)(brow + 4));
                acc[s] = __builtin_amdgcn_mfma_f32_16x16x32_bf16(a, b, acc[s], 0, 0, 0);
            }
        }
        // C/D layout: col(n) = lane&15, row(m) = quad*4 + r
#pragma unroll
        for (int r = 0; r < 4; r++) {
            int m = bm + quad * 4 + r;
            float s0 = rsqrtf((float)degree[m] + EPS);
#pragma unroll
            for (int s = 0; s < 4; s++)
                g[(size_t)m * DIM + bn + s * 16 + l16] = __float2bfloat16(s0 * acc[s][r]);
        }
    }
    __threadfence();
    grid.sync();

    // ---- phase 3: out[i] = relu(rsqrt(deg_i) * sum_j g[cols_i]); one wave per row, 4 rows/wave ----
    {
        const uint2* g2 = (const uint2*)g;  // row stride 64 uint2
        int wid = tid >> 6;    // 0..2047
        int lane = tid & 63;
        for (int row = wid; row < N_NODES; row += 2048) {
            int n = degree[row];
            const int* cl = cols + (size_t)row * MAXD;
            float s0[4] = {0.f,0.f,0.f,0.f}, s1[4] = {0.f,0.f,0.f,0.f};
            float s2[4] = {0.f,0.f,0.f,0.f}, s3[4] = {0.f,0.f,0.f,0.f};
            float s4[4] = {0.f,0.f,0.f,0.f}, s5[4] = {0.f,0.f,0.f,0.f};
            float s6[4] = {0.f,0.f,0.f,0.f}, s7[4] = {0.f,0.f,0.f,0.f};
            int i = 0;
            for (; i + 8 <= n; i += 8) {
                int4 ja = *(const int4*)(cl + i);
                int4 jb = *(const int4*)(cl + i + 4);
                uint2 u0 = g2[(size_t)ja.x * 64 + lane];
                uint2 u1 = g2[(size_t)ja.y * 64 + lane];
                uint2 u2 = g2[(size_t)ja.z * 64 + lane];
                uint2 u3 = g2[(size_t)ja.w * 64 + lane];
                uint2 u4 = g2[(size_t)jb.x * 64 + lane];
                uint2 u5 = g2[(size_t)jb.y * 64 + lane];
                uint2 u6 = g2[(size_t)jb.z * 64 + lane];
                uint2 u7 = g2[(size_t)jb.w * 64 + lane];
                s0[0] += bflo(u0.x); s0[1] += bfhi(u0.x); s0[2] += bflo(u0.y); s0[3] += bfhi(u0.y);
                s1[0] += bflo(u1.x); s1[1] += bfhi(u1.x); s1[2] += bflo(u1.y); s1[3] += bfhi(u1.y);
                s2[0] += bflo(u2.x); s2[1] += bfhi(u2.x); s2[2] += bflo(u2.y); s2[3] += bfhi(u2.y);
                s3[0] += bflo(u3.x); s3[1] += bfhi(u3.x); s3[2] += bflo(u3.y); s3[3] += bfhi(u3.y);
                s4[0] += bflo(u4.x); s4[1] += bfhi(u4.x); s4[2] += bflo(u4.y); s4[3] += bfhi(u4.y);
                s5[0] += bflo(u5.x); s5[1] += bfhi(u5.x); s5[2] += bflo(u5.y); s5[3] += bfhi(u5.y);
                s6[0] += bflo(u6.x); s6[1] += bfhi(u6.x); s6[2] += bflo(u6.y); s6[3] += bfhi(u6.y);
                s7[0] += bflo(u7.x); s7[1] += bfhi(u7.x); s7[2] += bflo(u7.y); s7[3] += bfhi(u7.y);
            }
            for (; i + 4 <= n; i += 4) {
                int4 ja = *(const int4*)(cl + i);
                uint2 u0 = g2[(size_t)ja.x * 64 + lane];
                uint2 u1 = g2[(size_t)ja.y * 64 + lane];
                uint2 u2 = g2[(size_t)ja.z * 64 + lane];
                uint2 u3 = g2[(size_t)ja.w * 64 + lane];
                s0[0] += bflo(u0.x); s0[1] += bfhi(u0.x); s0[2] += bflo(u0.y); s0[3] += bfhi(u0.y);
                s1[0] += bflo(u1.x); s1[1] += bfhi(u1.x); s1[2] += bflo(u1.y); s1[3] += bfhi(u1.y);
                s2[0] += bflo(u2.x); s2[1] += bfhi(u2.x); s2[2] += bflo(u2.y); s2[3] += bfhi(u2.y);
                s3[0] += bflo(u3.x); s3[1] += bfhi(u3.x); s3[2] += bflo(u3.y); s3[3] += bfhi(u3.y);
            }
            for (; i < n; i++) {
                uint2 u = g2[(size_t)cl[i] * 64 + lane];
                s0[0] += bflo(u.x); s0[1] += bfhi(u.x); s0[2] += bflo(u.y); s0[3] += bfhi(u.y);
            }
            float sc = rsqrtf((float)n + EPS);
            float4 o;
            o.x = fmaxf(sc * (((s0[0]+s1[0])+(s2[0]+s3[0])) + ((s4[0]+s5[0])+(s6[0]+s7[0]))), 0.f);
            o.y = fmaxf(sc * (((s0[1]+s1[1])+(s2[1]+s3[1])) + ((s4[1]+s5[1])+(s6[1]+s7[1]))), 0.f);
            o.z = fmaxf(sc * (((s0[2]+s1[2])+(s2[2]+s3[2])) + ((s4[2]+s5[2])+(s6[2]+s7[2]))), 0.f);
            o.w = fmaxf(sc * (((s0[3]+s1[3])+(s2[3]+s3[3])) + ((s4[3]+s5[3])+(s6[3]+s7[3]))), 0.f);
            *(float4*)(out + (size_t)row * DIM + lane * 4) = o;
        }
    }
}

extern "C" void kernel_launch(void* const* d_in, const int* in_sizes, int n_in,
                              void* d_out, int out_size, void* d_ws, size_t ws_size,
                              hipStream_t stream) {
    const float* x = (const float*)d_in[0];
    const int* ei = (const int*)d_in[1];   // [2, E] flat: rows then cols
    const float* W = (const float*)d_in[2];
    float* out = (float*)d_out;
    int E = in_sizes[1] / 2;

    unsigned char* ws = (unsigned char*)d_ws;
    size_t off = 0;
    unsigned* bitmap = (unsigned*)(ws + off); off += (size_t)N_NODES * WPR * 4;          // 8 MB
    int* degree = (int*)(ws + off);           off += (size_t)N_NODES * 4;                // 32 KB (contiguous with bitmap)
    int* cols = (int*)(ws + off);             off += (size_t)N_NODES * MAXD * 4;         // 4 MB
    __hip_bfloat16* g = (__hip_bfloat16*)(ws + off); off += (size_t)N_NODES * DIM * 2;   // 4 MB

    const int* erows = ei;
    const int* ecols = ei + E;
    void* args[] = {(void*)&x, (void*)&erows, (void*)&ecols, (void*)&W, (void*)&out,
                    (void*)&bitmap, (void*)&degree, (void*)&cols, (void*)&g, (void*)&E};
    hipLaunchCooperativeKernel((void*)gcn_fused, dim3(NBLK), dim3(NTHR), args, 0, stream);
}

// Round 6
// 118.144 us; speedup vs baseline: 3.7206x; 3.7206x over previous
//
#include <hip/hip_runtime.h>
#include <hip/hip_bf16.h>
#include <math.h>

#define N_NODES 8192
#define DIM 256
#define WPR 256   // bitmap words per row = 8192/32
#define MAXD 128  // max deduped neighbors per row (deduped degree ~ Poisson(33); P(>=128) ~ 0)
#define EPS 1e-5f

typedef __attribute__((ext_vector_type(8))) short bf16x8;
typedef __attribute__((ext_vector_type(4))) float f32x4;

__device__ inline float bfhi(unsigned u) { return __uint_as_float(u & 0xffff0000u); }
__device__ inline float bflo(unsigned u) { return __uint_as_float(u << 16); }

// ---------------- kernel 1: prep = convert(x,W -> bf16)  +  scatter(edges+diag -> dedup CSR)
// unit layout: [0, NX4)           convert x   (float4 -> bf16x4)
//              [NX4, NX4+NW4)     convert W
//              [NX4+NW4, +E+N)    scatter edge t (or diag pseudo-edge)
// The two works are independent (disjoint outputs); no intra-kernel ordering needed.
#define NX4 (N_NODES * DIM / 4)      // 524288
#define NW4 (DIM * DIM / 4)          // 16384
__global__ __launch_bounds__(256) void prep(const float* __restrict__ x,
                                            const float* __restrict__ W,
                                            const int* __restrict__ erows,
                                            const int* __restrict__ ecols,
                                            __hip_bfloat16* __restrict__ xb,
                                            __hip_bfloat16* __restrict__ Wb,
                                            unsigned* __restrict__ bitmap,
                                            int* __restrict__ degree,
                                            int* __restrict__ cols, int E) {
    int t = blockIdx.x * 256 + threadIdx.x;
    if (t < NX4 + NW4) {
        const float* src = (t < NX4) ? x : W;
        __hip_bfloat16* dst = (t < NX4) ? xb : Wb;
        size_t off = (size_t)((t < NX4) ? t : (t - NX4)) * 4;
        float4 v = *(const float4*)(src + off);
        union { __hip_bfloat16 h[4]; uint2 u; } p;
        p.h[0] = __float2bfloat16(v.x);
        p.h[1] = __float2bfloat16(v.y);
        p.h[2] = __float2bfloat16(v.z);
        p.h[3] = __float2bfloat16(v.w);
        *(uint2*)(dst + off) = p.u;
        return;
    }
    int e = t - (NX4 + NW4);
    if (e >= E + N_NODES) return;
    int r, c;
    if (e < E) { r = erows[e]; c = ecols[e]; }
    else       { r = e - E;    c = r; }       // diagonal pseudo-edge; set-dedups vs real (i,i)
    unsigned bit = 1u << (c & 31);
    unsigned old = atomicOr(&bitmap[(size_t)r * WPR + (c >> 5)], bit);
    if (!(old & bit)) {                        // exactly one thread sees each 0->1 transition
        int p = atomicAdd(&degree[r], 1);
        cols[(size_t)r * MAXD + p] = c;
    }
}

// ---------------- kernel 2: g = bf16( rsqrt(deg_m) .* (x @ W^T) ) via MFMA ----------------
// grid (128, 4); block 256 = 4 waves; wave computes 16(m) x 64(n); bf16 inputs (R2-proven)
__global__ __launch_bounds__(256) void gemm_mfma(const short* __restrict__ xb,
                                                 const short* __restrict__ Wb,
                                                 const int* __restrict__ degree,
                                                 __hip_bfloat16* __restrict__ g) {
    int wave = threadIdx.x >> 6;
    int lane = threadIdx.x & 63;
    int bm = blockIdx.x * 64 + wave * 16;
    int bn = blockIdx.y * 64;
    int quad = lane >> 4;
    int l16 = lane & 15;
    f32x4 acc[4] = {};
    const short* arow = xb + (size_t)(bm + l16) * DIM + quad * 8;
#pragma unroll
    for (int k0 = 0; k0 < DIM; k0 += 32) {
        bf16x8 a = *(const bf16x8*)(arow + k0);
#pragma unroll
        for (int s = 0; s < 4; s++) {
            bf16x8 b = *(const bf16x8*)(Wb + (size_t)(bn + s * 16 + l16) * DIM + k0 + quad * 8);
            acc[s] = __builtin_amdgcn_mfma_f32_16x16x32_bf16(a, b, acc[s], 0, 0, 0);
        }
    }
    // C/D layout: col(n) = lane&15, row(m) = quad*4 + r
#pragma unroll
    for (int r = 0; r < 4; r++) {
        int m = bm + quad * 4 + r;
        float s0 = rsqrtf((float)degree[m] + EPS);
#pragma unroll
        for (int s = 0; s < 4; s++)
            g[(size_t)m * DIM + bn + s * 16 + l16] = __float2bfloat16(s0 * acc[s][r]);
    }
}

// ---------------- kernel 3: out[i] = relu(rsqrt(deg_i) * sum_{j in cols(i)} g[j]) -------
// 2048 blocks x 256 thr; ONE WAVE PER ROW (8192 waves); 8 B bf16x4 gathers, 8-deep ILP
__global__ __launch_bounds__(256) void aggregate(const int* __restrict__ degree,
                                                 const int* __restrict__ cols,
                                                 const uint2* __restrict__ g2,  // row stride 64 uint2
                                                 float* __restrict__ out) {
    int wave = threadIdx.x >> 6;
    int lane = threadIdx.x & 63;
    int row = blockIdx.x * 4 + wave;
    int n = degree[row];                       // wave-uniform
    const int* cl = cols + (size_t)row * MAXD; // wave-uniform, 512 B aligned
    float s0[4] = {0.f,0.f,0.f,0.f}, s1[4] = {0.f,0.f,0.f,0.f};
    float s2[4] = {0.f,0.f,0.f,0.f}, s3[4] = {0.f,0.f,0.f,0.f};
    float s4[4] = {0.f,0.f,0.f,0.f}, s5[4] = {0.f,0.f,0.f,0.f};
    float s6[4] = {0.f,0.f,0.f,0.f}, s7[4] = {0.f,0.f,0.f,0.f};
    int i = 0;
    for (; i + 8 <= n; i += 8) {
        int4 ja = *(const int4*)(cl + i);
        int4 jb = *(const int4*)(cl + i + 4);
        uint2 u0 = g2[(size_t)ja.x * 64 + lane];
        uint2 u1 = g2[(size_t)ja.y * 64 + lane];
        uint2 u2 = g2[(size_t)ja.z * 64 + lane];
        uint2 u3 = g2[(size_t)ja.w * 64 + lane];
        uint2 u4 = g2[(size_t)jb.x * 64 + lane];
        uint2 u5 = g2[(size_t)jb.y * 64 + lane];
        uint2 u6 = g2[(size_t)jb.z * 64 + lane];
        uint2 u7 = g2[(size_t)jb.w * 64 + lane];
        s0[0] += bflo(u0.x); s0[1] += bfhi(u0.x); s0[2] += bflo(u0.y); s0[3] += bfhi(u0.y);
        s1[0] += bflo(u1.x); s1[1] += bfhi(u1.x); s1[2] += bflo(u1.y); s1[3] += bfhi(u1.y);
        s2[0] += bflo(u2.x); s2[1] += bfhi(u2.x); s2[2] += bflo(u2.y); s2[3] += bfhi(u2.y);
        s3[0] += bflo(u3.x); s3[1] += bfhi(u3.x); s3[2] += bflo(u3.y); s3[3] += bfhi(u3.y);
        s4[0] += bflo(u4.x); s4[1] += bfhi(u4.x); s4[2] += bflo(u4.y); s4[3] += bfhi(u4.y);
        s5[0] += bflo(u5.x); s5[1] += bfhi(u5.x); s5[2] += bflo(u5.y); s5[3] += bfhi(u5.y);
        s6[0] += bflo(u6.x); s6[1] += bfhi(u6.x); s6[2] += bflo(u6.y); s6[3] += bfhi(u6.y);
        s7[0] += bflo(u7.x); s7[1] += bfhi(u7.x); s7[2] += bflo(u7.y); s7[3] += bfhi(u7.y);
    }
    for (; i + 4 <= n; i += 4) {
        int4 ja = *(const int4*)(cl + i);
        uint2 u0 = g2[(size_t)ja.x * 64 + lane];
        uint2 u1 = g2[(size_t)ja.y * 64 + lane];
        uint2 u2 = g2[(size_t)ja.z * 64 + lane];
        uint2 u3 = g2[(size_t)ja.w * 64 + lane];
        s0[0] += bflo(u0.x); s0[1] += bfhi(u0.x); s0[2] += bflo(u0.y); s0[3] += bfhi(u0.y);
        s1[0] += bflo(u1.x); s1[1] += bfhi(u1.x); s1[2] += bflo(u1.y); s1[3] += bfhi(u1.y);
        s2[0] += bflo(u2.x); s2[1] += bfhi(u2.x); s2[2] += bflo(u2.y); s2[3] += bfhi(u2.y);
        s3[0] += bflo(u3.x); s3[1] += bfhi(u3.x); s3[2] += bflo(u3.y); s3[3] += bfhi(u3.y);
    }
    for (; i < n; i++) {
        uint2 u = g2[(size_t)cl[i] * 64 + lane];
        s0[0] += bflo(u.x); s0[1] += bfhi(u.x); s0[2] += bflo(u.y); s0[3] += bfhi(u.y);
    }
    float sc = rsqrtf((float)n + EPS);
    float4 o;
    o.x = fmaxf(sc * (((s0[0]+s1[0])+(s2[0]+s3[0])) + ((s4[0]+s5[0])+(s6[0]+s7[0]))), 0.f);
    o.y = fmaxf(sc * (((s0[1]+s1[1])+(s2[1]+s3[1])) + ((s4[1]+s5[1])+(s6[1]+s7[1]))), 0.f);
    o.z = fmaxf(sc * (((s0[2]+s1[2])+(s2[2]+s3[2])) + ((s4[2]+s5[2])+(s6[2]+s7[2]))), 0.f);
    o.w = fmaxf(sc * (((s0[3]+s1[3])+(s2[3]+s3[3])) + ((s4[3]+s5[3])+(s6[3]+s7[3]))), 0.f);
    *(float4*)(out + (size_t)row * DIM + lane * 4) = o;
}

extern "C" void kernel_launch(void* const* d_in, const int* in_sizes, int n_in,
                              void* d_out, int out_size, void* d_ws, size_t ws_size,
                              hipStream_t stream) {
    const float* x = (const float*)d_in[0];
    const int* ei = (const int*)d_in[1];   // [2, E] flat: rows then cols
    const float* W = (const float*)d_in[2];
    float* out = (float*)d_out;
    int E = in_sizes[1] / 2;

    unsigned char* ws = (unsigned char*)d_ws;
    size_t off = 0;
    unsigned* bitmap = (unsigned*)(ws + off); off += (size_t)N_NODES * WPR * 4;          // 8 MB
    int* degree = (int*)(ws + off);           off += (size_t)N_NODES * 4;                // 32 KB (contiguous with bitmap)
    int* cols = (int*)(ws + off);             off += (size_t)N_NODES * MAXD * 4;         // 4 MB
    __hip_bfloat16* xb = (__hip_bfloat16*)(ws + off); off += (size_t)N_NODES * DIM * 2;  // 4 MB
    __hip_bfloat16* Wb = (__hip_bfloat16*)(ws + off); off += (size_t)DIM * DIM * 2;      // 128 KB
    __hip_bfloat16* g = (__hip_bfloat16*)(ws + off);  off += (size_t)N_NODES * DIM * 2;  // 4 MB

    // one fill covers bitmap + degree (contiguous)
    hipMemsetAsync(bitmap, 0, (size_t)N_NODES * WPR * 4 + (size_t)N_NODES * 4, stream);
    int units = NX4 + NW4 + E + N_NODES;
    prep<<<(units + 255) / 256, 256, 0, stream>>>(x, W, ei, ei + E, xb, Wb, bitmap, degree, cols, E);
    dim3 ggrid(N_NODES / 64, DIM / 64);
    gemm_mfma<<<ggrid, 256, 0, stream>>>((const short*)xb, (const short*)Wb, degree, g);
    aggregate<<<N_NODES / 4, 256, 0, stream>>>(degree, cols, (const uint2*)g, out);
}

// Round 7
// 116.449 us; speedup vs baseline: 3.7747x; 1.0146x over previous
//
#include <hip/hip_runtime.h>
#include <hip/hip_bf16.h>
#include <math.h>

#define N_NODES 8192
#define DIM 256
#define WPR 256   // bitmap words per row = 8192/32
#define MAXD 128  // max deduped neighbors per row (deduped degree ~ Poisson(33); P(>=128) ~ 0)
#define EPS 1e-5f
#define ZWORDS (N_NODES * WPR + N_NODES)  // bitmap + degree, contiguous: 2,105,344 words

typedef __attribute__((ext_vector_type(8))) short bf16x8;
typedef __attribute__((ext_vector_type(4))) float f32x4;

__device__ inline float bfhi(unsigned u) { return __uint_as_float(u & 0xffff0000u); }
__device__ inline float bflo(unsigned u) { return __uint_as_float(u << 16); }

__device__ inline uint2 pack4(float4 v) {
    union { __hip_bfloat16 h[4]; uint2 u; } p;
    p.h[0] = __float2bfloat16(v.x);
    p.h[1] = __float2bfloat16(v.y);
    p.h[2] = __float2bfloat16(v.z);
    p.h[3] = __float2bfloat16(v.w);
    return p.u;
}

// ---------------- kernel 1: g = bf16(x @ W^T)  (unscaled)  +  zero bitmap/degree ----------
// grid (128, 4); block 256 = 4 waves; tile 64m x 64n; f32 inputs converted once per block
// into LDS (two K=128 halves; row pad 8 bf16 -> 272 B stride: 16B-aligned ds_read_b128,
// banks balanced ~2-way = free per m136).
// Side job: zero the bitmap+degree region (no ordering needed; scatter is a later node).
__global__ __launch_bounds__(256) void gemm_zero(const float* __restrict__ x,
                                                 const float* __restrict__ W,
                                                 __hip_bfloat16* __restrict__ g,
                                                 uint4* __restrict__ zreg) {
    // ---- zero side-job: 526336 uint4 over 512 blocks x 256 thr (grid-stride) ----
    {
        const int NZ4 = ZWORDS / 4;  // 526336
        int base = (blockIdx.y * 128 + blockIdx.x) * 256 + threadIdx.x;
        uint4 z = make_uint4(0, 0, 0, 0);
        for (int i = base; i < NZ4; i += 512 * 256) zreg[i] = z;
    }

    __shared__ __hip_bfloat16 As[64][136];  // [m][k-half], pad 8
    __shared__ __hip_bfloat16 Bs[64][136];  // [n][k-half]
    int tid = threadIdx.x;
    int wave = tid >> 6;
    int lane = tid & 63;
    int quad = lane >> 4;
    int l16 = lane & 15;
    int bm = blockIdx.x * 64;
    int bn = blockIdx.y * 64;
    f32x4 acc[4] = {};

    for (int kb = 0; kb < DIM; kb += 128) {
        // stage + convert: 64 rows x 32 float4 for each of A (x) and B (W)
        for (int i = tid; i < 64 * 32; i += 256) {
            int row = i >> 5;
            int c = (i & 31) * 4;
            float4 v = *(const float4*)&x[(size_t)(bm + row) * DIM + kb + c];
            *(uint2*)&As[row][c] = pack4(v);
            float4 w = *(const float4*)&W[(size_t)(bn + row) * DIM + kb + c];
            *(uint2*)&Bs[row][c] = pack4(w);
        }
        __syncthreads();
#pragma unroll
        for (int k0 = 0; k0 < 128; k0 += 32) {
            bf16x8 a = *(const bf16x8*)&As[wave * 16 + l16][k0 + quad * 8];
#pragma unroll
            for (int s = 0; s < 4; s++) {
                bf16x8 b = *(const bf16x8*)&Bs[s * 16 + l16][k0 + quad * 8];
                acc[s] = __builtin_amdgcn_mfma_f32_16x16x32_bf16(a, b, acc[s], 0, 0, 0);
            }
        }
        __syncthreads();
    }
    // C/D layout: col(n) = lane&15, row(m) = quad*4 + r  (R2/R6-proven)
#pragma unroll
    for (int r = 0; r < 4; r++) {
        int m = bm + wave * 16 + quad * 4 + r;
#pragma unroll
        for (int s = 0; s < 4; s++)
            g[(size_t)m * DIM + bn + s * 16 + l16] = __float2bfloat16(acc[s][r]);
    }
}

// ---------------- kernel 2: scatter edges + diagonal; dedup via atomicOr; build CSR ------
__global__ __launch_bounds__(256) void scatter_all(const int* __restrict__ erows,
                                                   const int* __restrict__ ecols,
                                                   unsigned* __restrict__ bitmap,
                                                   int* __restrict__ degree,
                                                   int* __restrict__ cols, int E) {
    int t = blockIdx.x * 256 + threadIdx.x;
    int r, c;
    if (t < E) {
        r = erows[t];
        c = ecols[t];
    } else if (t < E + N_NODES) {
        r = t - E;
        c = r;  // diagonal pseudo-edge; set-dedups vs real (i,i)
    } else {
        return;
    }
    unsigned bit = 1u << (c & 31);
    unsigned old = atomicOr(&bitmap[(size_t)r * WPR + (c >> 5)], bit);
    if (!(old & bit)) {  // exactly one thread sees each 0->1 transition
        int p = atomicAdd(&degree[r], 1);
        cols[(size_t)r * MAXD + p] = c;
    }
}

// ---------------- kernel 3: out[i] = relu(d_i * sum_j d_j * g[j]),  d = rsqrt(deg+eps) ---
// 2048 blocks x 256 thr; one wave per row; 8 B bf16x4 gathers, 8-deep ILP; d_j applied per
// term via broadcast degree load + v_rsq (FMA instead of ADD - free).
__global__ __launch_bounds__(256) void aggregate(const int* __restrict__ degree,
                                                 const int* __restrict__ cols,
                                                 const uint2* __restrict__ g2,  // row stride 64 uint2
                                                 float* __restrict__ out) {
    int wave = threadIdx.x >> 6;
    int lane = threadIdx.x & 63;
    int row = blockIdx.x * 4 + wave;
    int n = degree[row];                       // wave-uniform
    const int* cl = cols + (size_t)row * MAXD; // wave-uniform, 512 B aligned
    float s0[4] = {0.f,0.f,0.f,0.f}, s1[4] = {0.f,0.f,0.f,0.f};
    float s2[4] = {0.f,0.f,0.f,0.f}, s3[4] = {0.f,0.f,0.f,0.f};
    float s4[4] = {0.f,0.f,0.f,0.f}, s5[4] = {0.f,0.f,0.f,0.f};
    float s6[4] = {0.f,0.f,0.f,0.f}, s7[4] = {0.f,0.f,0.f,0.f};
    int i = 0;
    for (; i + 8 <= n; i += 8) {
        int4 ja = *(const int4*)(cl + i);
        int4 jb = *(const int4*)(cl + i + 4);
        float d0 = rsqrtf((float)degree[ja.x] + EPS);
        float d1 = rsqrtf((float)degree[ja.y] + EPS);
        float d2 = rsqrtf((float)degree[ja.z] + EPS);
        float d3 = rsqrtf((float)degree[ja.w] + EPS);
        float d4 = rsqrtf((float)degree[jb.x] + EPS);
        float d5 = rsqrtf((float)degree[jb.y] + EPS);
        float d6 = rsqrtf((float)degree[jb.z] + EPS);
        float d7 = rsqrtf((float)degree[jb.w] + EPS);
        uint2 u0 = g2[(size_t)ja.x * 64 + lane];
        uint2 u1 = g2[(size_t)ja.y * 64 + lane];
        uint2 u2 = g2[(size_t)ja.z * 64 + lane];
        uint2 u3 = g2[(size_t)ja.w * 64 + lane];
        uint2 u4 = g2[(size_t)jb.x * 64 + lane];
        uint2 u5 = g2[(size_t)jb.y * 64 + lane];
        uint2 u6 = g2[(size_t)jb.z * 64 + lane];
        uint2 u7 = g2[(size_t)jb.w * 64 + lane];
        s0[0] = fmaf(d0, bflo(u0.x), s0[0]); s0[1] = fmaf(d0, bfhi(u0.x), s0[1]);
        s0[2] = fmaf(d0, bflo(u0.y), s0[2]); s0[3] = fmaf(d0, bfhi(u0.y), s0[3]);
        s1[0] = fmaf(d1, bflo(u1.x), s1[0]); s1[1] = fmaf(d1, bfhi(u1.x), s1[1]);
        s1[2] = fmaf(d1, bflo(u1.y), s1[2]); s1[3] = fmaf(d1, bfhi(u1.y), s1[3]);
        s2[0] = fmaf(d2, bflo(u2.x), s2[0]); s2[1] = fmaf(d2, bfhi(u2.x), s2[1]);
        s2[2] = fmaf(d2, bflo(u2.y), s2[2]); s2[3] = fmaf(d2, bfhi(u2.y), s2[3]);
        s3[0] = fmaf(d3, bflo(u3.x), s3[0]); s3[1] = fmaf(d3, bfhi(u3.x), s3[1]);
        s3[2] = fmaf(d3, bflo(u3.y), s3[2]); s3[3] = fmaf(d3, bfhi(u3.y), s3[3]);
        s4[0] = fmaf(d4, bflo(u4.x), s4[0]); s4[1] = fmaf(d4, bfhi(u4.x), s4[1]);
        s4[2] = fmaf(d4, bflo(u4.y), s4[2]); s4[3] = fmaf(d4, bfhi(u4.y), s4[3]);
        s5[0] = fmaf(d5, bflo(u5.x), s5[0]); s5[1] = fmaf(d5, bfhi(u5.x), s5[1]);
        s5[2] = fmaf(d5, bflo(u5.y), s5[2]); s5[3] = fmaf(d5, bfhi(u5.y), s5[3]);
        s6[0] = fmaf(d6, bflo(u6.x), s6[0]); s6[1] = fmaf(d6, bfhi(u6.x), s6[1]);
        s6[2] = fmaf(d6, bflo(u6.y), s6[2]); s6[3] = fmaf(d6, bfhi(u6.y), s6[3]);
        s7[0] = fmaf(d7, bflo(u7.x), s7[0]); s7[1] = fmaf(d7, bfhi(u7.x), s7[1]);
        s7[2] = fmaf(d7, bflo(u7.y), s7[2]); s7[3] = fmaf(d7, bfhi(u7.y), s7[3]);
    }
    for (; i + 4 <= n; i += 4) {
        int4 ja = *(const int4*)(cl + i);
        float d0 = rsqrtf((float)degree[ja.x] + EPS);
        float d1 = rsqrtf((float)degree[ja.y] + EPS);
        float d2 = rsqrtf((float)degree[ja.z] + EPS);
        float d3 = rsqrtf((float)degree[ja.w] + EPS);
        uint2 u0 = g2[(size_t)ja.x * 64 + lane];
        uint2 u1 = g2[(size_t)ja.y * 64 + lane];
        uint2 u2 = g2[(size_t)ja.z * 64 + lane];
        uint2 u3 = g2[(size_t)ja.w * 64 + lane];
        s0[0] = fmaf(d0, bflo(u0.x), s0[0]); s0[1] = fmaf(d0, bfhi(u0.x), s0[1]);
        s0[2] = fmaf(d0, bflo(u0.y), s0[2]); s0[3] = fmaf(d0, bfhi(u0.y), s0[3]);
        s1[0] = fmaf(d1, bflo(u1.x), s1[0]); s1[1] = fmaf(d1, bfhi(u1.x), s1[1]);
        s1[2] = fmaf(d1, bflo(u1.y), s1[2]); s1[3] = fmaf(d1, bfhi(u1.y), s1[3]);
        s2[0] = fmaf(d2, bflo(u2.x), s2[0]); s2[1] = fmaf(d2, bfhi(u2.x), s2[1]);
        s2[2] = fmaf(d2, bflo(u2.y), s2[2]); s2[3] = fmaf(d2, bfhi(u2.y), s2[3]);
        s3[0] = fmaf(d3, bflo(u3.x), s3[0]); s3[1] = fmaf(d3, bfhi(u3.x), s3[1]);
        s3[2] = fmaf(d3, bflo(u3.y), s3[2]); s3[3] = fmaf(d3, bfhi(u3.y), s3[3]);
    }
    for (; i < n; i++) {
        int j = cl[i];
        float d = rsqrtf((float)degree[j] + EPS);
        uint2 u = g2[(size_t)j * 64 + lane];
        s0[0] = fmaf(d, bflo(u.x), s0[0]); s0[1] = fmaf(d, bfhi(u.x), s0[1]);
        s0[2] = fmaf(d, bflo(u.y), s0[2]); s0[3] = fmaf(d, bfhi(u.y), s0[3]);
    }
    float sc = rsqrtf((float)n + EPS);
    float4 o;
    o.x = fmaxf(sc * (((s0[0]+s1[0])+(s2[0]+s3[0])) + ((s4[0]+s5[0])+(s6[0]+s7[0]))), 0.f);
    o.y = fmaxf(sc * (((s0[1]+s1[1])+(s2[1]+s3[1])) + ((s4[1]+s5[1])+(s6[1]+s7[1]))), 0.f);
    o.z = fmaxf(sc * (((s0[2]+s1[2])+(s2[2]+s3[2])) + ((s4[2]+s5[2])+(s6[2]+s7[2]))), 0.f);
    o.w = fmaxf(sc * (((s0[3]+s1[3])+(s2[3]+s3[3])) + ((s4[3]+s5[3])+(s6[3]+s7[3]))), 0.f);
    *(float4*)(out + (size_t)row * DIM + lane * 4) = o;
}

extern "C" void kernel_launch(void* const* d_in, const int* in_sizes, int n_in,
                              void* d_out, int out_size, void* d_ws, size_t ws_size,
                              hipStream_t stream) {
    const float* x = (const float*)d_in[0];
    const int* ei = (const int*)d_in[1];   // [2, E] flat: rows then cols
    const float* W = (const float*)d_in[2];
    float* out = (float*)d_out;
    int E = in_sizes[1] / 2;

    unsigned char* ws = (unsigned char*)d_ws;
    size_t off = 0;
    unsigned* bitmap = (unsigned*)(ws + off); off += (size_t)N_NODES * WPR * 4;          // 8 MB
    int* degree = (int*)(ws + off);           off += (size_t)N_NODES * 4;                // 32 KB (contiguous with bitmap)
    int* cols = (int*)(ws + off);             off += (size_t)N_NODES * MAXD * 4;         // 4 MB
    __hip_bfloat16* g = (__hip_bfloat16*)(ws + off); off += (size_t)N_NODES * DIM * 2;   // 4 MB

    // node 1: GEMM (no degree dependency) + zero bitmap/degree for the next node
    dim3 ggrid(N_NODES / 64, DIM / 64);
    gemm_zero<<<ggrid, 256, 0, stream>>>(x, W, g, (uint4*)bitmap);
    // node 2: dedup scatter -> CSR
    int total = E + N_NODES;
    scatter_all<<<(total + 255) / 256, 256, 0, stream>>>(ei, ei + E, bitmap, degree, cols, E);
    // node 3: normalized aggregate + relu
    aggregate<<<N_NODES / 4, 256, 0, stream>>>(degree, cols, (const uint2*)g, out);
}